// Round 5
// baseline (10662.576 us; speedup 1.0000x reference)
//
#include <hip/hip_runtime.h>
#include <hip/hip_bf16.h>

// 2-layer LSTM, B=64, F=128, T=1024, H=512. Output = h_T of layer 1 (64x512 fp32).
// R5: NO acquire fence / NO buffer_inv anywhere (R4 spent ~7.7us/iter on protocol;
// the per-iter agent-acquire = full XCD-L2 invalidate x32/XCD/iter, forcing L2
// re-miss of x/flags/h every step: FETCH_SIZE 719MB for a ~50MB problem).
// Coherence now entirely via L2-bypassing (sc0 sc1) accesses to the L3 point:
//  - h reads:  relaxed AGENT-scope u64 atomic loads (global_load_dwordx2 sc0 sc1)
//  - h writes: relaxed AGENT-scope dword atomic stores (write-through), vmcnt-drained
//    by __syncthreads() before the flag post
//  - flags:    relaxed AGENT-scope dword store + poll (1 flag line per thread)
// Reader-side ordering is the poll's control dependency + s_barrier (no VMEM
// speculation past the unresolved poll branch). Read-only data (x, weights) now
// stays warm in L1/L2 across all 1024 iterations.
// Topology unchanged from R4: 256 WGs x 256 thr, layer-split (wg<128: layer 0,
// 80 weight-VGPRs/lane; wg>=128: layer 1, 128), weights in registers/AGPRs,
// 4-generation h rotation, gate reshuffle via tiny LDS stage.

#define B_ 64
#define F_ 128
#define T_ 1024
#define H_ 512
#define NWG 256

typedef __bf16 bf16x8 __attribute__((ext_vector_type(8)));
typedef float f32x4 __attribute__((ext_vector_type(4)));

__device__ __forceinline__ float sigm(float x) { return 1.0f / (1.0f + __expf(-x)); }
__device__ __forceinline__ float tanh_fast(float x) { return 1.0f - 2.0f / (__expf(2.0f * x) + 1.0f); }

// L2-bypassing (coherence-point) bf16x8 load: two relaxed agent u64 atomic loads.
__device__ __forceinline__ bf16x8 load_h8(const unsigned long long* base, int idx64) {
  unsigned long long lo = __hip_atomic_load(base + idx64,     __ATOMIC_RELAXED, __HIP_MEMORY_SCOPE_AGENT);
  unsigned long long hi = __hip_atomic_load(base + idx64 + 1, __ATOMIC_RELAXED, __HIP_MEMORY_SCOPE_AGENT);
  union { unsigned long long q[2]; bf16x8 v; } u;
  u.q[0] = lo; u.q[1] = hi;
  return u.v;
}

// x (B,F,T) fp32 -> xT (T,B,F) bf16
__global__ __launch_bounds__(256) void transpose_x_kernel(const float* __restrict__ x,
                                                          __bf16* __restrict__ xT) {
  __shared__ float tile[F_][65];
  const int bb = blockIdx.x >> 4;
  const int tt = blockIdx.x & 15;
  const int tid = threadIdx.x;
  const int tl = tid & 63;
  const int f0 = tid >> 6;
  for (int fo = 0; fo < F_; fo += 4) {
    int f = fo + f0;
    tile[f][tl] = x[((size_t)bb * F_ + f) * T_ + tt * 64 + tl];
  }
  __syncthreads();
  const int fw = tid & 127;
  const int tg = tid >> 7;
  for (int to = 0; to < 64; to += 2) {
    int t = to + tg;
    xT[((size_t)(tt * 64 + t) * B_ + bb) * F_ + fw] = (__bf16)tile[fw][t];
  }
}

__global__ __launch_bounds__(256, 1) void lstm_persistent(
    const __bf16* __restrict__ xT,
    const float* __restrict__ Wih0, const float* __restrict__ Whh0,
    const float* __restrict__ bih0, const float* __restrict__ bhh0,
    const float* __restrict__ Wih1, const float* __restrict__ Whh1,
    const float* __restrict__ bih1, const float* __restrict__ bhh1,
    __bf16* h0_pub, __bf16* h1_pub,   // each: [4][B][H] bf16, 4-gen rotation
    unsigned* flags,                   // [NWG] x 64B lines, monotone counters
    float* __restrict__ out) {
  __shared__ float sG[4][272];   // gate reshuffle staging, stride 68 (conflict-free)

  const int wg   = blockIdx.x;
  const int tid  = threadIdx.x;
  const int wv   = tid >> 6;
  const int lane = tid & 63;
  const int p    = lane >> 4;        // quad
  const int l15  = lane & 15;
  const int b    = wv * 16 + l15;    // batch
  const int ks   = p * 8;            // k offset inside a 32-chunk
  const int col4 = (wg & 127) * 4;   // this WG's 4 h-columns
  const int row  = (l15 >> 2) * H_ + col4 + (l15 & 3);  // A-frag gate row for m=l15

  if (wg < 128) {
    // ---------------- layer 0 ----------------
    bf16x8 wh[16], wi[4];
    {
      const float* s = Whh0 + (size_t)row * H_ + ks;
#pragma unroll
      for (int kc = 0; kc < 16; ++kc) {
        bf16x8 a;
#pragma unroll
        for (int j = 0; j < 8; ++j) a[j] = (__bf16)s[kc * 32 + j];
        wh[kc] = a;
      }
      const float* si = Wih0 + (size_t)row * F_ + ks;
#pragma unroll
      for (int kc = 0; kc < 4; ++kc) {
        bf16x8 a;
#pragma unroll
        for (int j = 0; j < 8; ++j) a[j] = (__bf16)si[kc * 32 + j];
        wi[kc] = a;
      }
    }
    float bq[4];
#pragma unroll
    for (int r = 0; r < 4; ++r) {
      const int grow = p * H_ + col4 + r;
      bq[r] = bih0[grow] + bhh0[grow];
    }

    // x frags for it=0 (prefetched thereafter between flag-post and poll)
    bf16x8 xb[4];
#pragma unroll
    for (int kc = 0; kc < 4; ++kc)
      xb[kc] = *(const bf16x8*)&xT[(size_t)b * F_ + kc * 32 + ks];

    float c0 = 0.f;
    for (int it = 0; it < T_; ++it) {
      const unsigned long long* h0r =
          (const unsigned long long*)(h0_pub + ((it + 3) & 3) * (B_ * H_));
      unsigned* h0w = (unsigned*)(h0_pub + (it & 3) * (B_ * H_));

      f32x4 acc  = {0.f, 0.f, 0.f, 0.f};
      f32x4 accb = {0.f, 0.f, 0.f, 0.f};
#pragma unroll
      for (int kc = 0; kc < 16; ++kc) {
        bf16x8 hb0 = load_h8(h0r, (b * H_ + kc * 32 + ks) >> 2);
        acc = __builtin_amdgcn_mfma_f32_16x16x32_bf16(wh[kc], hb0, acc, 0, 0, 0);
      }
#pragma unroll
      for (int kc = 0; kc < 4; ++kc)
        accb = __builtin_amdgcn_mfma_f32_16x16x32_bf16(wi[kc], xb[kc], accb, 0, 0, 0);

#pragma unroll
      for (int r = 0; r < 4; ++r) {
        float v = acc[r] + accb[r] + bq[r];
        sG[wv][p * 68 + r * 16 + l15] = (p == 2) ? tanh_fast(v) : sigm(v);
      }
      __syncthreads();
      float gi = sG[wv][0 * 68 + p * 16 + l15];
      float gf = sG[wv][1 * 68 + p * 16 + l15];
      float gg = sG[wv][2 * 68 + p * 16 + l15];
      float go = sG[wv][3 * 68 + p * 16 + l15];
      c0 = gf * c0 + gi * gg;
      float h = go * tanh_fast(c0);

      union { __bf16 bf; unsigned short u; } cv; cv.bf = (__bf16)h;
      unsigned o = (unsigned)__shfl_xor((int)(unsigned)cv.u, 16, 64);
      if ((p & 1) == 0) {
        unsigned v = (unsigned)cv.u | (o << 16);
        __hip_atomic_store(h0w + b * (H_ / 2) + (col4 >> 1) + (p >> 1), v,
                           __ATOMIC_RELAXED, __HIP_MEMORY_SCOPE_AGENT);
      }

      // ---- barrier (no fence): drain -> post -> (x prefetch) -> poll -> barrier ----
      const unsigned tgt = (unsigned)(it + 1);
      __syncthreads();   // s_waitcnt vmcnt(0) before s_barrier: publishes at L3
      if (tid == 0)
        __hip_atomic_store(&flags[wg * 16], tgt, __ATOMIC_RELAXED, __HIP_MEMORY_SCOPE_AGENT);
      if (it + 1 < T_) { // prefetch next x while others arrive
        const __bf16* xrow = xT + ((size_t)(it + 1) * B_ + b) * F_;
#pragma unroll
        for (int kc = 0; kc < 4; ++kc) xb[kc] = *(const bf16x8*)&xrow[kc * 32 + ks];
      }
      while (__hip_atomic_load(&flags[tid * 16], __ATOMIC_RELAXED,
                               __HIP_MEMORY_SCOPE_AGENT) < tgt)
        __builtin_amdgcn_s_sleep(1);
      __syncthreads();   // all 256 WGs arrived; h reads may start
    }
  } else {
    // ---------------- layer 1 ----------------
    bf16x8 wi[16], wh[16];
    {
      const float* s0 = Wih1 + (size_t)row * H_ + ks;
      const float* s1 = Whh1 + (size_t)row * H_ + ks;
#pragma unroll
      for (int kc = 0; kc < 16; ++kc) {
        bf16x8 a, c;
#pragma unroll
        for (int j = 0; j < 8; ++j) {
          a[j] = (__bf16)s0[kc * 32 + j];
          c[j] = (__bf16)s1[kc * 32 + j];
        }
        wi[kc] = a; wh[kc] = c;
      }
    }
    float bq[4];
#pragma unroll
    for (int r = 0; r < 4; ++r) {
      const int grow = p * H_ + col4 + r;
      bq[r] = bih1[grow] + bhh1[grow];
    }

    float c1 = 0.f;
    // participate in barrier for it=0 (layer-1 idle that step)
    {
      __syncthreads();
      if (tid == 0)
        __hip_atomic_store(&flags[wg * 16], 1u, __ATOMIC_RELAXED, __HIP_MEMORY_SCOPE_AGENT);
      while (__hip_atomic_load(&flags[tid * 16], __ATOMIC_RELAXED,
                               __HIP_MEMORY_SCOPE_AGENT) < 1u)
        __builtin_amdgcn_s_sleep(1);
      __syncthreads();
    }
    for (int it = 1; it <= T_; ++it) {
      const unsigned long long* h0r =
          (const unsigned long long*)(h0_pub + ((it + 3) & 3) * (B_ * H_));
      const unsigned long long* h1r =
          (const unsigned long long*)(h1_pub + ((it + 3) & 3) * (B_ * H_));
      unsigned* h1w = (unsigned*)(h1_pub + (it & 3) * (B_ * H_));

      f32x4 acca = {0.f, 0.f, 0.f, 0.f};
      f32x4 accc = {0.f, 0.f, 0.f, 0.f};
#pragma unroll
      for (int kc = 0; kc < 16; ++kc) {
        const int i64 = (b * H_ + kc * 32 + ks) >> 2;
        bf16x8 hb0 = load_h8(h0r, i64);
        bf16x8 hb1 = load_h8(h1r, i64);
        acca = __builtin_amdgcn_mfma_f32_16x16x32_bf16(wi[kc], hb0, acca, 0, 0, 0);
        accc = __builtin_amdgcn_mfma_f32_16x16x32_bf16(wh[kc], hb1, accc, 0, 0, 0);
      }
#pragma unroll
      for (int r = 0; r < 4; ++r) {
        float v = acca[r] + accc[r] + bq[r];
        sG[wv][p * 68 + r * 16 + l15] = (p == 2) ? tanh_fast(v) : sigm(v);
      }
      __syncthreads();
      float gi = sG[wv][0 * 68 + p * 16 + l15];
      float gf = sG[wv][1 * 68 + p * 16 + l15];
      float gg = sG[wv][2 * 68 + p * 16 + l15];
      float go = sG[wv][3 * 68 + p * 16 + l15];
      c1 = gf * c1 + gi * gg;
      float h = go * tanh_fast(c1);

      if (it < T_) {
        union { __bf16 bf; unsigned short u; } cv; cv.bf = (__bf16)h;
        unsigned o = (unsigned)__shfl_xor((int)(unsigned)cv.u, 16, 64);
        if ((p & 1) == 0) {
          unsigned v = (unsigned)cv.u | (o << 16);
          __hip_atomic_store(h1w + b * (H_ / 2) + (col4 >> 1) + (p >> 1), v,
                             __ATOMIC_RELAXED, __HIP_MEMORY_SCOPE_AGENT);
        }
        const unsigned tgt = (unsigned)(it + 1);
        __syncthreads();
        if (tid == 0)
          __hip_atomic_store(&flags[wg * 16], tgt, __ATOMIC_RELAXED, __HIP_MEMORY_SCOPE_AGENT);
        while (__hip_atomic_load(&flags[tid * 16], __ATOMIC_RELAXED,
                                 __HIP_MEMORY_SCOPE_AGENT) < tgt)
          __builtin_amdgcn_s_sleep(1);
        __syncthreads();
      } else {
        out[b * H_ + col4 + p] = h;   // final h1[T-1], fp32
      }
    }
  }
}

// Workspace layout:
//   [0]        flags: 256 x 64B = 16 KiB
//   [16384]    h0_pub: 4 gens x 64x512x2B = 262144 B
//   [278528]   h1_pub: 262144 B
//   [1 MiB]    xT: 16 MiB
// Zeroed region: [0, 540672).
extern "C" void kernel_launch(void* const* d_in, const int* in_sizes, int n_in,
                              void* d_out, int out_size, void* d_ws, size_t ws_size,
                              hipStream_t stream) {
  const float* x    = (const float*)d_in[0];
  const float* Wih0 = (const float*)d_in[1];
  const float* Whh0 = (const float*)d_in[2];
  const float* bih0 = (const float*)d_in[3];
  const float* bhh0 = (const float*)d_in[4];
  const float* Wih1 = (const float*)d_in[5];
  const float* Whh1 = (const float*)d_in[6];
  const float* bih1 = (const float*)d_in[7];
  const float* bhh1 = (const float*)d_in[8];
  float* out = (float*)d_out;

  char* ws = (char*)d_ws;
  unsigned* flags = (unsigned*)ws;
  __bf16* h0p = (__bf16*)(ws + 16384);
  __bf16* h1p = (__bf16*)(ws + 16384 + 4 * B_ * H_ * 2);
  __bf16* xT  = (__bf16*)(ws + (1 << 20));

  hipMemsetAsync(ws, 0, 16384 + 8 * B_ * H_ * 2, stream);

  transpose_x_kernel<<<dim3(B_ * 16), dim3(256), 0, stream>>>(x, xT);

  lstm_persistent<<<dim3(NWG), dim3(256), 0, stream>>>(
      xT, Wih0, Whh0, bih0, bhh0, Wih1, Whh1, bih1, bhh1,
      h0p, h1p, flags, out);
}

// Round 6
// 8829.576 us; speedup vs baseline: 1.2076x; 1.2076x over previous
//
#include <hip/hip_runtime.h>
#include <hip/hip_bf16.h>

// 2-layer LSTM, B=64, F=128, T=1024, H=512. Output = h_T of layer 1 (64x512 fp32).
// R6: master-relay barrier + merged 512-thread WGs + occupancy pinning.
//  - 128 WGs x 512 thr. Waves 0-3: layer 0 (batch tiles), waves 4-7: layer 1.
//    Per-lane weight frags stay split (L0: 20 frags, L1: 32) -> no R3-style spill;
//    union VGPR (~190) + 55.3 KB LDS pin EXACTLY 1 WG/CU -> kills the replay
//    degradation (R3/R4/R5: 51/48/60 ms worst) attributed to WG->CU packing.
//  - Barrier: per-WG arrival flag (tid0 store) -> master WG0 polls 128 lines in
//    parallel -> posts single epoch word -> only tid0 of each WG polls epoch.
//    Replaces the 65k-thread poll storm (~4 MB/round of L2-bypass traffic).
//  - Coherence: R4's proven scheme (normal dwordx4 h reads + per-iter wave0
//    acquire fence; sc0sc1 relaxed-agent publish stores drained by the
//    compiler's vmcnt(0)-before-s_barrier; 4-generation h rotation).

#define B_ 64
#define F_ 128
#define T_ 1024
#define H_ 512
#define NWG 128

typedef __bf16 bf16x8 __attribute__((ext_vector_type(8)));
typedef float f32x4 __attribute__((ext_vector_type(4)));

__device__ __forceinline__ float sigm(float x) { return 1.0f / (1.0f + __expf(-x)); }
__device__ __forceinline__ float tanh_fast(float x) { return 1.0f - 2.0f / (__expf(2.0f * x) + 1.0f); }

// x (B,F,T) fp32 -> xT (T,B,F) bf16
__global__ __launch_bounds__(256) void transpose_x_kernel(const float* __restrict__ x,
                                                          __bf16* __restrict__ xT) {
  __shared__ float tile[F_][65];
  const int bb = blockIdx.x >> 4;
  const int tt = blockIdx.x & 15;
  const int tid = threadIdx.x;
  const int tl = tid & 63;
  const int f0 = tid >> 6;
  for (int fo = 0; fo < F_; fo += 4) {
    int f = fo + f0;
    tile[f][tl] = x[((size_t)bb * F_ + f) * T_ + tt * 64 + tl];
  }
  __syncthreads();
  const int fw = tid & 127;
  const int tg = tid >> 7;
  for (int to = 0; to < 64; to += 2) {
    int t = to + tg;
    xT[((size_t)(tt * 64 + t) * B_ + bb) * F_ + fw] = (__bf16)tile[fw][t];
  }
}

__global__ __launch_bounds__(512, 1) void lstm_persistent(
    const __bf16* __restrict__ xT,
    const float* __restrict__ Wih0, const float* __restrict__ Whh0,
    const float* __restrict__ bih0, const float* __restrict__ bhh0,
    const float* __restrict__ Wih1, const float* __restrict__ Whh1,
    const float* __restrict__ bih1, const float* __restrict__ bhh1,
    __bf16* h0_pub, __bf16* h1_pub,   // each: [4][B][H] bf16, 4-gen rotation
    unsigned* flags,                   // [NWG] x 64B arrival lines
    unsigned* epoch,                   // single release word (own line)
    float* __restrict__ out) {
  // 8 wave-private gate rows; stride 1728 floats inflates LDS to 55,296 B so
  // LDS caps residency at 2 WG/CU and VGPR (>=130 x 8 waves) caps it at 1.
  __shared__ float sG[8][1728];

  const int wg   = blockIdx.x;       // 0..127
  const int tid  = threadIdx.x;      // 0..511
  const int wv   = tid >> 6;         // 0..7
  const int lane = tid & 63;
  const int p    = lane >> 4;        // quad
  const int l15  = lane & 15;
  const bool isL0 = (wv < 4);
  const int b    = (wv & 3) * 16 + l15;   // batch
  const int ks   = p * 8;                 // k offset inside a 32-chunk
  const int col4 = wg * 4;                // this WG's 4 h-columns (both layers)
  const int row  = (l15 >> 2) * H_ + col4 + (l15 & 3);  // A-frag gate row

  // ---- Prologue: weights -> registers (per-wave layer split) ----
  bf16x8 wA[16], wB[16], wI[4];
  float bq[4];
  if (isL0) {
    const float* s = Whh0 + (size_t)row * H_ + ks;
#pragma unroll
    for (int kc = 0; kc < 16; ++kc) {
      bf16x8 a;
#pragma unroll
      for (int j = 0; j < 8; ++j) a[j] = (__bf16)s[kc * 32 + j];
      wA[kc] = a;
    }
    const float* si = Wih0 + (size_t)row * F_ + ks;
#pragma unroll
    for (int kc = 0; kc < 4; ++kc) {
      bf16x8 a;
#pragma unroll
      for (int j = 0; j < 8; ++j) a[j] = (__bf16)si[kc * 32 + j];
      wI[kc] = a;
    }
#pragma unroll
    for (int r = 0; r < 4; ++r) {
      const int grow = p * H_ + col4 + r;
      bq[r] = bih0[grow] + bhh0[grow];
    }
  } else {
    const float* s0 = Wih1 + (size_t)row * H_ + ks;
    const float* s1 = Whh1 + (size_t)row * H_ + ks;
#pragma unroll
    for (int kc = 0; kc < 16; ++kc) {
      bf16x8 a, c;
#pragma unroll
      for (int j = 0; j < 8; ++j) {
        a[j] = (__bf16)s0[kc * 32 + j];
        c[j] = (__bf16)s1[kc * 32 + j];
      }
      wA[kc] = a; wB[kc] = c;
    }
#pragma unroll
    for (int r = 0; r < 4; ++r) {
      const int grow = p * H_ + col4 + r;
      bq[r] = bih1[grow] + bhh1[grow];
    }
  }

  // initial x frags (L0 waves), prefetched each iter thereafter
  bf16x8 xb[4];
  if (isL0) {
#pragma unroll
    for (int kc = 0; kc < 4; ++kc)
      xb[kc] = *(const bf16x8*)&xT[(size_t)b * F_ + kc * 32 + ks];
  }

  float cc = 0.f;   // c0 for L0 waves, c1 for L1 waves

  for (int it = 0; it <= T_; ++it) {
    const int gr = (it + 3) & 3;   // read generation (it-1)
    const int gw = it & 3;         // write generation (it)
    const bool act = isL0 ? (it < T_) : (it >= 1);

    if (act) {
      f32x4 acc  = {0.f, 0.f, 0.f, 0.f};
      f32x4 acc2 = {0.f, 0.f, 0.f, 0.f};
      if (isL0) {
        const __bf16* h0r = h0_pub + gr * (B_ * H_);
#pragma unroll
        for (int kc = 0; kc < 16; ++kc) {
          bf16x8 hb0 = *(const bf16x8*)&h0r[b * H_ + kc * 32 + ks];
          acc = __builtin_amdgcn_mfma_f32_16x16x32_bf16(wA[kc], hb0, acc, 0, 0, 0);
        }
#pragma unroll
        for (int kc = 0; kc < 4; ++kc)
          acc2 = __builtin_amdgcn_mfma_f32_16x16x32_bf16(wI[kc], xb[kc], acc2, 0, 0, 0);
      } else {
        const __bf16* h0r = h0_pub + gr * (B_ * H_);
        const __bf16* h1r = h1_pub + gr * (B_ * H_);
#pragma unroll
        for (int kc = 0; kc < 16; ++kc) {
          bf16x8 hb0 = *(const bf16x8*)&h0r[b * H_ + kc * 32 + ks];
          bf16x8 hb1 = *(const bf16x8*)&h1r[b * H_ + kc * 32 + ks];
          acc  = __builtin_amdgcn_mfma_f32_16x16x32_bf16(wA[kc], hb0, acc,  0, 0, 0);
          acc2 = __builtin_amdgcn_mfma_f32_16x16x32_bf16(wB[kc], hb1, acc2, 0, 0, 0);
        }
      }
#pragma unroll
      for (int r = 0; r < 4; ++r) {
        float v = acc[r] + acc2[r] + bq[r];
        sG[wv][p * 68 + r * 16 + l15] = (p == 2) ? tanh_fast(v) : sigm(v);
      }
    }
    __syncthreads();   // gate staging visible (all 8 waves, uniform count)

    if (act) {
      float gi = sG[wv][0 * 68 + p * 16 + l15];
      float gf = sG[wv][1 * 68 + p * 16 + l15];
      float gg = sG[wv][2 * 68 + p * 16 + l15];
      float go = sG[wv][3 * 68 + p * 16 + l15];
      cc = gf * cc + gi * gg;
      float h = go * tanh_fast(cc);

      if (isL0 || it < T_) {
        union { __bf16 bf; unsigned short u; } cv; cv.bf = (__bf16)h;
        unsigned o = (unsigned)__shfl_xor((int)(unsigned)cv.u, 16, 64);
        if ((p & 1) == 0) {
          unsigned v = (unsigned)cv.u | (o << 16);
          unsigned* hw = (unsigned*)((isL0 ? h0_pub : h1_pub) + gw * (B_ * H_));
          __hip_atomic_store(hw + b * (H_ / 2) + (col4 >> 1) + (p >> 1), v,
                             __ATOMIC_RELAXED, __HIP_MEMORY_SCOPE_AGENT);
        }
      } else {
        out[b * H_ + col4 + p] = h;   // it == T: final h1[T-1], fp32
      }
    }

    if (it != T_) {
      // ---- master-relay epoch barrier ----
      const unsigned tgt = (unsigned)(it + 1);
      __syncthreads();   // compiler drains vmcnt(0) before s_barrier: publishes acked
      if (tid == 0)
        __hip_atomic_store(&flags[wg * 16], tgt, __ATOMIC_RELAXED, __HIP_MEMORY_SCOPE_AGENT);
      if (isL0 && (it + 1) < T_) {   // prefetch next x while waiting
        const __bf16* xrow = xT + ((size_t)(it + 1) * B_ + b) * F_;
#pragma unroll
        for (int kc = 0; kc < 4; ++kc) xb[kc] = *(const bf16x8*)&xrow[kc * 32 + ks];
      }
      if (wg == 0) {
        if (tid < NWG) {   // master: poll all arrival lines in parallel
          while (__hip_atomic_load(&flags[tid * 16], __ATOMIC_RELAXED,
                                   __HIP_MEMORY_SCOPE_AGENT) < tgt)
            __builtin_amdgcn_s_sleep(1);
        }
        __syncthreads();   // master saw all arrivals
        if (tid == 0)
          __hip_atomic_store(epoch, tgt, __ATOMIC_RELAXED, __HIP_MEMORY_SCOPE_AGENT);
      } else {
        if (tid == 0) {    // only ONE poller per WG
          while (__hip_atomic_load(epoch, __ATOMIC_RELAXED,
                                   __HIP_MEMORY_SCOPE_AGENT) < tgt)
            __builtin_amdgcn_s_sleep(1);
        }
        __syncthreads();   // release whole WG
      }
      if (tid < 64)        // acquire: drop stale L1/L2 h lines (proven R4 scheme)
        __builtin_amdgcn_fence(__ATOMIC_ACQUIRE, "agent");
      __syncthreads();     // no wave issues h loads before the inv
    }
  }
}

// Workspace layout:
//   [0]        flags: 128 x 64B = 8 KiB
//   [8192]     epoch: 4 B (own line)
//   [16384]    h0_pub: 4 gens x 64x512x2B = 262144 B
//   [278528]   h1_pub: 262144 B
//   [1 MiB]    xT: 16 MiB
// Zeroed region: [0, 540672).
extern "C" void kernel_launch(void* const* d_in, const int* in_sizes, int n_in,
                              void* d_out, int out_size, void* d_ws, size_t ws_size,
                              hipStream_t stream) {
  const float* x    = (const float*)d_in[0];
  const float* Wih0 = (const float*)d_in[1];
  const float* Whh0 = (const float*)d_in[2];
  const float* bih0 = (const float*)d_in[3];
  const float* bhh0 = (const float*)d_in[4];
  const float* Wih1 = (const float*)d_in[5];
  const float* Whh1 = (const float*)d_in[6];
  const float* bih1 = (const float*)d_in[7];
  const float* bhh1 = (const float*)d_in[8];
  float* out = (float*)d_out;

  char* ws = (char*)d_ws;
  unsigned* flags = (unsigned*)ws;
  unsigned* epoch = (unsigned*)(ws + 8192);
  __bf16* h0p = (__bf16*)(ws + 16384);
  __bf16* h1p = (__bf16*)(ws + 16384 + 4 * B_ * H_ * 2);
  __bf16* xT  = (__bf16*)(ws + (1 << 20));

  hipMemsetAsync(ws, 0, 16384 + 8 * B_ * H_ * 2, stream);

  transpose_x_kernel<<<dim3(B_ * 16), dim3(256), 0, stream>>>(x, xT);

  lstm_persistent<<<dim3(NWG), dim3(512), 0, stream>>>(
      xT, Wih0, Whh0, bih0, bhh0, Wih1, Whh1, bih1, bhh1,
      h0p, h1p, flags, epoch, out);
}